// Round 3
// baseline (186.808 us; speedup 1.0000x reference)
//
#include <hip/hip_runtime.h>

#define IN_CH 256
#define IMG_W 56
#define BAND  28                // output rows per block
#define LROWS 29                // loaded input rows per band (28 + 1 halo row)
#define CH_F  (LROWS * IMG_W)   // 1624 floats per channel in LDS (no padding)

typedef __attribute__((address_space(1))) const void GBuf;
typedef __attribute__((address_space(3))) void LBuf;

// out[b,c0] = conv3x3(x[b,c0], w[2c0])   + conv3x3(x[b,c1], w[2c1+1])
// out[b,c1] = conv3x3(x[b,c1], w[2c1])   + conv3x3(x[b,c0], w[2c0+1]),  c1 = c0^4
// One block per (pair, batch, 28-row band). LDS holds 29 raw rows x 2 ch,
// staged with global_load_lds (linear both sides). Halo via cndmask in compute.
// Each thread computes a 2-row x 4-col strip for both channels (16 outputs).
__global__ __launch_bounds__(256, 6) void dwconv_butterfly(
    const float* __restrict__ x, const float* __restrict__ wgt,
    float* __restrict__ out)
{
    __shared__ float lds[2 * CH_F];   // 12992 B

    const int tid  = threadIdx.x;
    const int p    = blockIdx.x;      // 0..127
    const int b    = blockIdx.y;      // 0..31
    const int band = blockIdx.z;      // 0..1
    const int c0   = ((p >> 2) << 3) | (p & 3);   // bit2 == 0
    const int c1   = c0 ^ 4;

    const size_t chan = 56u * 56u;
    const float* x0 = x + ((size_t)b * IN_CH + c0) * chan;
    const float* x1 = x + ((size_t)b * IN_CH + c1) * chan;
    float* o0 = out + ((size_t)b * IN_CH + c0) * chan + (size_t)band * BAND * IMG_W;
    float* o1 = out + ((size_t)b * IN_CH + c1) * chan + (size_t)band * BAND * IMG_W;

    // band0: global rows 0..28 -> lds rows 0..28 ; band1: rows 27..55 -> 0..28
    const int gbase = band ? 27 : 0;
    const float* g0 = x0 + gbase * IMG_W;   // 1624 contiguous floats
    const float* g1 = x1 + gbase * IMG_W;

    // ---- async stage: 812 x 16B chunks; LDS linear, global linear per ch ----
    // chunk q: q<406 -> ch0 floats 4q..4q+3 ; else ch1 floats 4(q-406)..
    {
        const int wbase = tid & ~63;          // wave-uniform lds base chunk
#pragma unroll
        for (int k = 0; k < 3; ++k) {
            const int q = tid + 256 * k;      // < 768
            const float* src = (q < 406) ? (g0 + 4 * q) : (g1 + 4 * (q - 406));
            __builtin_amdgcn_global_load_lds((GBuf*)src,
                (LBuf*)&lds[4 * (256 * k + wbase)], 16, 0, 0);
        }
        if (tid < 44) {                       // chunks 768..811 (wave 0 only)
            const float* src = g1 + 4 * (768 + tid - 406);
            __builtin_amdgcn_global_load_lds((GBuf*)src,
                (LBuf*)&lds[4 * 768], 16, 0, 0);
        }
    }

    // ---- weights (wave-uniform -> scalar loads, overlap with staging) ----
    float wa[9], wb[9], wc[9], wd[9];
    {
        const float* pa = wgt + (size_t)(2 * c0) * 9;
        const float* pb = wgt + (size_t)(2 * c1 + 1) * 9;
        const float* pc = wgt + (size_t)(2 * c1) * 9;
        const float* pd = wgt + (size_t)(2 * c0 + 1) * 9;
#pragma unroll
        for (int i = 0; i < 9; ++i) {
            wa[i] = pa[i]; wb[i] = pb[i]; wc[i] = pc[i]; wd[i] = pd[i];
        }
    }

    __syncthreads();   // drains global_load_lds (vmcnt) + barrier

    // ---- compute: 196 strips of 2 rows x 4 cols, both channels ----
    if (tid < 196) {
        const int rp  = tid / 14;             // 0..13 row-pair
        const int w0  = (tid - rp * 14) * 4;  // 0,4,..,52
        const int oh0 = rp * 2;               // band-local out row base
        // lds rows needed: rbase..rbase+3 ; W[j+kh] serves out row oh0+j, tap kh
        const int rbase = oh0 - 1 + band;     // band0: oh0-1 ; band1: oh0

        const bool has_l = (w0 > 0);
        const bool has_r = (w0 < 52);
        const int  col_l = has_l ? (w0 - 1) : 0;    // clamped (value masked)
        const int  col_r = has_r ? (w0 + 4) : 55;

        float W[4][12];   // [row][ch*6 + c] ; c=0: col w0-1, c=1..4: w0..w0+3, c=5: w0+4
#pragma unroll
        for (int rr = 0; rr < 4; ++rr) {
            const int r  = rbase + rr;
            // only rr==0 (band0, oh0==0) or rr==3 (band1, oh0==26) can be out of range
            const bool zr = (rr == 0) ? (r < 0) : ((rr == 3) ? (r > 28) : false);
            const int  rc = (rr == 0) ? (r < 0 ? 0 : r) : ((rr == 3) ? (r > 28 ? 28 : r) : r);
            const float* p0 = &lds[rc * IMG_W + w0];        // 16B aligned
            const float* p1 = p0 + CH_F;
            const float4 a0 = *(const float4*)p0;
            const float4 a1 = *(const float4*)p1;
            const float l0 = lds[rc * IMG_W + col_l];
            const float r0 = lds[rc * IMG_W + col_r];
            const float l1 = lds[CH_F + rc * IMG_W + col_l];
            const float r1 = lds[CH_F + rc * IMG_W + col_r];
            W[rr][0]  = (zr || !has_l) ? 0.f : l0;
            W[rr][1]  = zr ? 0.f : a0.x;
            W[rr][2]  = zr ? 0.f : a0.y;
            W[rr][3]  = zr ? 0.f : a0.z;
            W[rr][4]  = zr ? 0.f : a0.w;
            W[rr][5]  = (zr || !has_r) ? 0.f : r0;
            W[rr][6]  = (zr || !has_l) ? 0.f : l1;
            W[rr][7]  = zr ? 0.f : a1.x;
            W[rr][8]  = zr ? 0.f : a1.y;
            W[rr][9]  = zr ? 0.f : a1.z;
            W[rr][10] = zr ? 0.f : a1.w;
            W[rr][11] = (zr || !has_r) ? 0.f : r1;
        }

        float acc[2][8];  // [j][ch*4 + i]
#pragma unroll
        for (int j = 0; j < 2; ++j)
#pragma unroll
            for (int i = 0; i < 8; ++i) acc[j][i] = 0.f;

#pragma unroll
        for (int j = 0; j < 2; ++j) {
#pragma unroll
            for (int kh = 0; kh < 3; ++kh) {
                const int rw = j + kh;        // static 0..3
#pragma unroll
                for (int kw = 0; kw < 3; ++kw) {
                    const float fa = wa[kh * 3 + kw], fb = wb[kh * 3 + kw];
                    const float fc = wc[kh * 3 + kw], fd = wd[kh * 3 + kw];
#pragma unroll
                    for (int i = 0; i < 4; ++i) {
                        const float u0 = W[rw][i + kw];
                        const float u1 = W[rw][6 + i + kw];
                        acc[j][i]     += u0 * fa + u1 * fb;
                        acc[j][4 + i] += u1 * fc + u0 * fd;
                    }
                }
            }
        }

#pragma unroll
        for (int j = 0; j < 2; ++j) {
            float* q0 = o0 + (oh0 + j) * IMG_W + w0;
            float* q1 = o1 + (oh0 + j) * IMG_W + w0;
            *(float4*)q0 = make_float4(acc[j][0], acc[j][1], acc[j][2], acc[j][3]);
            *(float4*)q1 = make_float4(acc[j][4], acc[j][5], acc[j][6], acc[j][7]);
        }
    }
}

extern "C" void kernel_launch(void* const* d_in, const int* in_sizes, int n_in,
                              void* d_out, int out_size, void* d_ws, size_t ws_size,
                              hipStream_t stream) {
    const float* x = (const float*)d_in[0];   // (32, 256, 56, 56) fp32
    const float* w = (const float*)d_in[1];   // (512, 1, 3, 3)   fp32
    float* out = (float*)d_out;               // (32, 256, 56, 56) fp32

    dim3 grid(IN_CH / 2, 32, 2);  // 128 pairs x 32 batch x 2 bands
    dim3 block(256);
    dwconv_butterfly<<<grid, block, 0, stream>>>(x, w, out);
}